// Round 2
// 418.558 us; speedup vs baseline: 1.0406x; 1.0406x over previous
//
#include <hip/hip_runtime.h>
#include <hip/hip_bf16.h>
#include <cstdint>

#define N_HEAD 16
#define HEAD_DIM 128

typedef __bf16 bf16;
typedef __bf16 bf16x8 __attribute__((ext_vector_type(8)));
typedef __bf16 bf16x4 __attribute__((ext_vector_type(4)));
typedef float f32x4 __attribute__((ext_vector_type(4)));

// async global->LDS 16B (per-lane lds addr must be base + lane*16)
__device__ __forceinline__ void gload_lds16(const void* g, void* l) {
  auto gp = reinterpret_cast<const __attribute__((address_space(1))) char*>(
      reinterpret_cast<uintptr_t>(g));
  auto lp = reinterpret_cast<__attribute__((address_space(3))) char*>(
      reinterpret_cast<uintptr_t>(l));
  __builtin_amdgcn_global_load_lds(gp, lp, 16, 0, 0);
}

// ------- fp32 -> bf16 convert, all 5 tensors in one launch (z selects) ------
__global__ __launch_bounds__(256) void cvt_all(
    const float* __restrict__ x, const float* __restrict__ Wq,
    const float* __restrict__ Wk, const float* __restrict__ Wv,
    const float* __restrict__ Wp, bf16* __restrict__ xb,
    bf16* __restrict__ wqkv, bf16* __restrict__ wpb, int nx4, int nw4) {
  const int z = blockIdx.z;
  const float* in;
  bf16* out;
  int n4;
  if (z == 0)      { in = x;  out = xb;  n4 = nx4; }
  else if (z == 1) { in = Wq; out = wqkv;                     n4 = nw4; }
  else if (z == 2) { in = Wk; out = wqkv + (size_t)nw4 * 4;   n4 = nw4; }
  else if (z == 3) { in = Wv; out = wqkv + (size_t)nw4 * 8;   n4 = nw4; }
  else             { in = Wp; out = wpb;  n4 = nw4; }
  const int i = blockIdx.x * 256 + threadIdx.x;
  if (i >= n4) return;
  const float4 f = reinterpret_cast<const float4*>(in)[i];
  bf16x4 o;
  o.x = (bf16)f.x; o.y = (bf16)f.y; o.z = (bf16)f.z; o.w = (bf16)f.w;
  reinterpret_cast<bf16x4*>(out)[i] = o;
}

// ---------------- GEMM: C[M,N] = A[M,K] * B[N,K]^T (both row-major, bf16) ----
// (kept for the projection GEMM: 512 blocks at 128^2 beats 128 idle-half-GPU
//  blocks at 256^2 for M=4096,N=2048)
template <typename OutT>
__global__ __launch_bounds__(256) void gemm_bt(
    const bf16* __restrict__ A, const bf16* __restrict__ Bt,
    OutT* __restrict__ C, int M, int N, int K) {
  __shared__ __align__(16) bf16 As[2][128 * 32];
  __shared__ __align__(16) bf16 Bs[2][128 * 32];
  const int tid = threadIdx.x;
  const int lane = tid & 63;
  const int wave = tid >> 6;
  const int wm = (wave >> 1) * 64;
  const int wn = (wave & 1) * 64;
  const int lr = lane & 15;
  const int lk = (lane >> 4) * 8;

  const bf16* Ab = A + (size_t)blockIdx.y * 128 * K;
  const bf16* Bb = Bt + (size_t)blockIdx.x * 128 * K;

  const int r0 = tid >> 2;        // 0..63, +64 on second pass
  const int c0 = (tid & 3) * 8;   // k-offset in elements

  f32x4 acc[4][4] = {};

  for (int k0 = 0; k0 < K; k0 += 64) {
    __syncthreads();
#pragma unroll
    for (int s = 0; s < 2; ++s) {
      const int kk = k0 + s * 32 + c0;
      gload_lds16(Ab + (size_t)r0 * K + kk, As[s] + (size_t)tid * 8);
      gload_lds16(Ab + (size_t)(r0 + 64) * K + kk, As[s] + (size_t)(256 + tid) * 8);
      gload_lds16(Bb + (size_t)r0 * K + kk, Bs[s] + (size_t)tid * 8);
      gload_lds16(Bb + (size_t)(r0 + 64) * K + kk, Bs[s] + (size_t)(256 + tid) * 8);
    }
    __syncthreads();

#pragma unroll
    for (int s = 0; s < 2; ++s) {
      bf16x8 a[4], b[4];
#pragma unroll
      for (int i = 0; i < 4; ++i)
        a[i] = *reinterpret_cast<const bf16x8*>(As[s] + (wm + i * 16 + lr) * 32 + lk);
#pragma unroll
      for (int j = 0; j < 4; ++j)
        b[j] = *reinterpret_cast<const bf16x8*>(Bs[s] + (wn + j * 16 + lr) * 32 + lk);
#pragma unroll
      for (int i = 0; i < 4; ++i)
#pragma unroll
        for (int j = 0; j < 4; ++j)
          acc[i][j] = __builtin_amdgcn_mfma_f32_16x16x32_bf16(a[i], b[j], acc[i][j], 0, 0, 0);
    }
  }

  const int orow = blockIdx.y * 128 + wm + (lane >> 4) * 4;
  const int ocol = blockIdx.x * 128 + wn + lr;
#pragma unroll
  for (int i = 0; i < 4; ++i)
#pragma unroll
    for (int j = 0; j < 4; ++j)
#pragma unroll
      for (int r = 0; r < 4; ++r)
        C[(size_t)(orow + i * 16 + r) * N + (ocol + j * 16)] = (OutT)acc[i][j][r];
}

// ---------------- 256x256 8-phase GEMM (bf16 in/out), used for QKV ----------
// BM=BN=256, BK=64, 512 threads (8 waves = 2Mx4N), per-wave C = 128x64.
// Double-buffered LDS 128 KiB. Per phase: {ds_read frags | issue 1 half-tile
// global_load_lds | (counted vmcnt at phase 4/8) | s_barrier | MFMA quadrant
// under setprio(1) | s_barrier}.  Steady state keeps 2 half-tiles (vmcnt 4)
// riding across barriers; never drains to 0 in the main loop.
// LDS swizzle: byte ^= (row&7)<<4, applied on the PRE-SWIZZLED GLOBAL SOURCE
// (linear global_load_lds dest) and on every ds_read address (involution).
// Liveness-checked stage map (bufA=steps 2i, bufB=steps 2i+1):
//  p1: bufB.A0  p2: bufB.A1  p3: bufA'.B0  p4: bufA'.B1 + vmcnt(4)
//  p5: bufA'.A0 p6: bufA'.A1 p7: bufB'.B0  p8: bufB'.B1 + vmcnt(4)
// each target is staged strictly after the barrier of the phase where its
// previous contents were last read (B dies after p1/p5, A after p4/p8);
// ds_reads of a phase are consumed by that phase's MFMA (compiler lgkmcnt)
// before the phase-end barrier, so a later-phase stage cannot race them.
__global__ __launch_bounds__(512, 2) void gemm256(
    const bf16* __restrict__ A, const bf16* __restrict__ Bt,
    bf16* __restrict__ C, int M, int N, int K) {
  __shared__ __align__(16) char sA[2][32768];
  __shared__ __align__(16) char sB[2][32768];

  // XCD-bijective swizzle (nwg % 8 == 0 for our shapes), M-fastest so each
  // XCD owns 3 B-panels (3 MB, L2-resident) and streams A.
  const int nwgy = M >> 8;
  const int nwg = (N >> 8) * nwgy;
  const int q8 = nwg >> 3;
  const int wgid = (blockIdx.x & 7) * q8 + (blockIdx.x >> 3);
  const int by = wgid % nwgy;
  const int bx = wgid / nwgy;

  const int tid = threadIdx.x;
  const int lane = tid & 63;
  const int wave = tid >> 6;
  const int wm = (wave >> 2) << 7;   // 0 / 128
  const int wn = (wave & 3) << 6;    // 0..192
  const int lr = lane & 15;
  const int lk16 = (lane >> 4) << 4; // quad's 16B k-group
  const int sx = (lr & 7) << 4;      // read-side swizzle XOR (row&7)<<4

  const bf16* Ab = A + (size_t)by * 256 * K;
  const bf16* Bb = Bt + (size_t)bx * 256 * K;

  // staging geometry: half-tile = 128 rows x 64 k (16 KB); 2 passes/thread.
  // physical lds offset o = pp*8192 + tid*16 -> row=o>>7,
  // logical col byte = (o&127) ^ ((row&7)<<4)  (source pre-swizzle)
  int srow[2], scol[2];
#pragma unroll
  for (int pp = 0; pp < 2; ++pp) {
    const int o = pp * 8192 + tid * 16;
    srow[pp] = o >> 7;
    scol[pp] = (o & 127) ^ ((srow[pp] & 7) << 4);
  }

  auto stageA = [&](int buf, int half, int k0) {
#pragma unroll
    for (int pp = 0; pp < 2; ++pp)
      gload_lds16(Ab + (size_t)(half * 128 + srow[pp]) * K + k0 + (scol[pp] >> 1),
                  sA[buf] + half * 16384 + pp * 8192 + tid * 16);
  };
  auto stageB = [&](int buf, int half, int k0) {
#pragma unroll
    for (int pp = 0; pp < 2; ++pp)
      gload_lds16(Bb + (size_t)(half * 128 + srow[pp]) * K + k0 + (scol[pp] >> 1),
                  sB[buf] + half * 16384 + pp * 8192 + tid * 16);
  };

  f32x4 acc[8][4] = {};
  bf16x8 bF[4][2];

#define VMCNT4                                             \
  asm volatile("s_waitcnt vmcnt(4)" ::: "memory");         \
  __builtin_amdgcn_sched_barrier(0)
#define VMCNT0                                             \
  asm volatile("s_waitcnt vmcnt(0)" ::: "memory");         \
  __builtin_amdgcn_sched_barrier(0)

#define PHASE(BUF, P, STAGE, WAIT)                                             \
  {                                                                            \
    bf16x8 aF[2][2];                                                           \
    if (P == 0) {                                                              \
      _Pragma("unroll") for (int n = 0; n < 4; ++n)                            \
      _Pragma("unroll") for (int ks = 0; ks < 2; ++ks)                         \
        bF[n][ks] = *reinterpret_cast<const bf16x8*>(                          \
            sB[BUF] + (wn + n * 16 + lr) * 128 + ((ks * 64 + lk16) ^ sx));     \
    }                                                                          \
    _Pragma("unroll") for (int mi = 0; mi < 2; ++mi)                           \
    _Pragma("unroll") for (int ks = 0; ks < 2; ++ks)                           \
      aF[mi][ks] = *reinterpret_cast<const bf16x8*>(                           \
          sA[BUF] + (wm + (P * 2 + mi) * 16 + lr) * 128 +                      \
          ((ks * 64 + lk16) ^ sx));                                            \
    STAGE;                                                                     \
    WAIT;                                                                      \
    __builtin_amdgcn_s_barrier();                                              \
    __builtin_amdgcn_s_setprio(1);                                             \
    _Pragma("unroll") for (int ks = 0; ks < 2; ++ks)                           \
    _Pragma("unroll") for (int mi = 0; mi < 2; ++mi)                           \
    _Pragma("unroll") for (int n = 0; n < 4; ++n)                              \
      acc[P * 2 + mi][n] = __builtin_amdgcn_mfma_f32_16x16x32_bf16(            \
          aF[mi][ks], bF[n][ks], acc[P * 2 + mi][n], 0, 0, 0);                 \
    __builtin_amdgcn_s_setprio(0);                                             \
    __builtin_amdgcn_s_barrier();                                              \
  }

  const int nIt = K >> 7;  // 2 K-steps (BK=64) per iteration

  // prologue: buf0 full tile + buf1 B-halves; drain buf0, keep buf1.B flying
  stageB(0, 0, 0); stageB(0, 1, 0);
  stageA(0, 0, 0); stageA(0, 1, 0);
  stageB(1, 0, 64); stageB(1, 1, 64);
  VMCNT4;
  __builtin_amdgcn_s_barrier();

  int k0 = 0;
  for (int it = 0; it < nIt - 1; ++it, k0 += 128) {
    PHASE(0, 0, stageA(1, 0, k0 + 64), );
    PHASE(0, 1, stageA(1, 1, k0 + 64), );
    PHASE(0, 2, stageB(0, 0, k0 + 128), );
    PHASE(0, 3, stageB(0, 1, k0 + 128), VMCNT4);
    PHASE(1, 0, stageA(0, 0, k0 + 128), );
    PHASE(1, 1, stageA(0, 1, k0 + 128), );
    PHASE(1, 2, stageB(1, 0, k0 + 192), );
    PHASE(1, 3, stageB(1, 1, k0 + 192), VMCNT4);
  }
  // final iteration: only buf1's A-halves still need staging
  PHASE(0, 0, stageA(1, 0, k0 + 64), );
  PHASE(0, 1, stageA(1, 1, k0 + 64), );
  PHASE(0, 2, , );
  PHASE(0, 3, , VMCNT0);
  PHASE(1, 0, , );
  PHASE(1, 1, , );
  PHASE(1, 2, , );
  PHASE(1, 3, , );
#undef PHASE
#undef VMCNT4
#undef VMCNT0

  const int orow = by * 256 + wm + (lane >> 4) * 4;
  const int ocol = bx * 256 + wn + lr;
#pragma unroll
  for (int m = 0; m < 8; ++m)
#pragma unroll
    for (int n = 0; n < 4; ++n)
#pragma unroll
      for (int r = 0; r < 4; ++r)
        C[(size_t)(orow + m * 16 + r) * N + (ocol + n * 16)] = (bf16)acc[m][n][r];
}

// ---------------- rope + rms-norm, in-place on q,k inside qkv buffer --------
__global__ __launch_bounds__(256) void rope_rms(
    bf16* __restrict__ qkv, const float* __restrict__ cs,
    const float* __restrict__ sn, int T) {
  const int C = N_HEAD * HEAD_DIM;
  const int S = 3 * C;
  const int bt = blockIdx.x;
  const int t = bt % T;
  const int wave = threadIdx.x >> 6;
  const int lane = threadIdx.x & 63;
  const int h = blockIdx.y * 4 + wave;
  bf16* p = qkv + (size_t)bt * S + (blockIdx.z ? C : 0) + h * HEAD_DIM;
  // q: 1.2 * 0.08838834764831845 * 1.4426950408889634 (exp2-domain softmax)
  const float oscale = blockIdx.z ? 1.2f : 0.15302091809294977f;
  const float c = cs[t * 64 + lane];
  const float s = sn[t * 64 + lane];
  const float x1 = (float)p[lane];
  const float x2 = (float)p[lane + 64];
  const float r1 = x1 * c + x2 * s;
  const float r2 = x2 * c - x1 * s;
  float ss = r1 * r1 + r2 * r2;
#pragma unroll
  for (int m = 1; m < 64; m <<= 1) ss += __shfl_xor(ss, m);
  const float sc = oscale * rsqrtf(ss * (1.0f / 128.0f) + 1e-6f);
  p[lane] = (bf16)(r1 * sc);
  p[lane + 64] = (bf16)(r2 * sc);
}

// ---------------- gate + transpose: vT[b][h][d][t] = v[b][t][h][d] + gate*ve --
__global__ __launch_bounds__(256) void gate_transpose(
    const bf16* __restrict__ qkv, const float* __restrict__ x,
    const float* __restrict__ ve, const float* __restrict__ Wg,
    bf16* __restrict__ vT, int T) {
  const int C = N_HEAD * HEAD_DIM;
  const int S = 3 * C;
  const int t0 = blockIdx.x * 64;
  const int c0 = blockIdx.y * 64;
  const int b = blockIdx.z;
  const int h = c0 >> 7;

  __shared__ float gs[64];
  __shared__ __align__(16) bf16 tile[64][72];

  if (threadIdx.x < 64) {
    const float* xr = x + (size_t)(b * T + t0 + threadIdx.x) * C;
    float a = 0.f;
#pragma unroll
    for (int j = 0; j < 12; ++j) a += xr[j] * Wg[h * 12 + j];
    gs[threadIdx.x] = 3.f / (1.f + __expf(-a));
  }
  __syncthreads();

  {
    const int r = threadIdx.x >> 2;
    const int cc = (threadIdx.x & 3) * 16;
    const size_t vrow = (size_t)(b * T + t0 + r) * S + 2 * C + c0 + cc;
    const size_t erow = (size_t)(b * T + t0 + r) * C + c0 + cc;
    bf16x8 a0 = *reinterpret_cast<const bf16x8*>(qkv + vrow);
    bf16x8 a1 = *reinterpret_cast<const bf16x8*>(qkv + vrow + 8);
    const float g = gs[r];
    bf16x8 o0, o1;
#pragma unroll
    for (int i = 0; i < 8; ++i) o0[i] = (bf16)((float)a0[i] + g * ve[erow + i]);
#pragma unroll
    for (int i = 0; i < 8; ++i) o1[i] = (bf16)((float)a1[i] + g * ve[erow + 8 + i]);
    *reinterpret_cast<bf16x8*>(&tile[r][cc]) = o0;
    *reinterpret_cast<bf16x8*>(&tile[r][cc + 8]) = o1;
  }
  __syncthreads();
  {
    const int dr = threadIdx.x >> 2;        // col of tile = d offset
    const int tc = (threadIdx.x & 3) * 16;  // row of tile = t offset
    bf16x8 o0, o1;
#pragma unroll
    for (int i = 0; i < 8; ++i) o0[i] = tile[tc + i][dr];
#pragma unroll
    for (int i = 0; i < 8; ++i) o1[i] = tile[tc + 8 + i][dr];
    const size_t orow =
        ((size_t)((b * N_HEAD + h) * HEAD_DIM) + (c0 & 127) + dr) * T + t0 + tc;
    *reinterpret_cast<bf16x8*>(vT + orow) = o0;
    *reinterpret_cast<bf16x8*>(vT + orow + 8) = o1;
  }
}

// ---------------- flash attention, sliding window, LDS-staged --------------
__global__ __launch_bounds__(256, 2) void attn(
    const bf16* __restrict__ qkv, const bf16* __restrict__ vT,
    bf16* __restrict__ y, const int* __restrict__ wptr, int T, int B) {
  const int C = N_HEAD * HEAD_DIM;
  const int S = 3 * C;
  const int nq = T >> 7;                       // q-blocks per (b,h)
  const int ppx = (B * N_HEAD) >> 3;           // (b,h) pairs per XCD
  const int bid = blockIdx.x;
  const int xcd = bid & 7;
  const int sl = bid >> 3;
  const int pair = xcd * ppx + sl / nq;
  const int qi = sl % nq;
  const int b = pair / N_HEAD;
  const int h = pair % N_HEAD;
  const int qb = qi * 128;

  const int tid = threadIdx.x;
  const int wave = tid >> 6;
  const int lane = tid & 63;
  const int lm = lane & 15;
  const int quad = lane >> 4;

  const int w = wptr[0];
  const int W = (w > 0 && w < T) ? w : (1 << 30);

  __shared__ __align__(16) bf16 Ks[4][64][32];   // [d-chunk][key][32]  16 KB
  __shared__ __align__(16) bf16 Vs[2][128][32];  // [key-chunk][d][32]  16 KB
  __shared__ __align__(16) bf16 Pb[4][16][72];   // per-wave P[q][64key]  9 KB

  const bf16* kb = qkv + (size_t)b * T * S + C + (size_t)h * HEAD_DIM;
  const bf16* vb = vT + (size_t)((b * N_HEAD + h) * HEAD_DIM) * T;  // [128][T]

  const int qt[2] = {qb + wave * 16, qb + 64 + wave * 16};
  bf16x8 qf[2][4];
#pragma unroll
  for (int t = 0; t < 2; ++t) {
    const bf16* qrow = qkv + (size_t)(b * T + qt[t] + lm) * S + h * HEAD_DIM;
#pragma unroll
    for (int c = 0; c < 4; ++c)
      qf[t][c] = *reinterpret_cast<const bf16x8*>(qrow + c * 32 + quad * 8);
  }

  float mrun[2] = {-1e30f, -1e30f}, lrun[2] = {0.f, 0.f};
  f32x4 oacc[2][8] = {};

  int kstart = qb - W;
  if (kstart < 0) kstart = 0;
  kstart &= ~63;
  const int kend = qb + 64;  // last chunk start

  const int sr = tid >> 2;       // staging row 0..63
  const int sc = (tid & 3) * 8;  // staging col offset (elements)

  bf16x8 kpre[4], vpre[4];
  {
    const bf16* kr = kb + (size_t)(kstart + sr) * S + sc;
#pragma unroll
    for (int c = 0; c < 4; ++c)
      kpre[c] = *reinterpret_cast<const bf16x8*>(kr + c * 32);
#pragma unroll
    for (int c2 = 0; c2 < 2; ++c2)
#pragma unroll
      for (int i = 0; i < 2; ++i)
        vpre[c2 * 2 + i] = *reinterpret_cast<const bf16x8*>(
            vb + (size_t)(i * 64 + sr) * T + kstart + c2 * 32 + sc);
  }

  for (int kc = kstart; kc <= kend; kc += 64) {
    __syncthreads();
#pragma unroll
    for (int c = 0; c < 4; ++c)
      *reinterpret_cast<bf16x8*>(&Ks[c][sr][sc]) = kpre[c];
#pragma unroll
    for (int c2 = 0; c2 < 2; ++c2)
#pragma unroll
      for (int i = 0; i < 2; ++i)
        *reinterpret_cast<bf16x8*>(&Vs[c2][i * 64 + sr][sc]) = vpre[c2 * 2 + i];
    __syncthreads();

    if (kc + 64 <= kend) {
      const int kc2 = kc + 64;
      const bf16* kr = kb + (size_t)(kc2 + sr) * S + sc;
#pragma unroll
      for (int c = 0; c < 4; ++c)
        kpre[c] = *reinterpret_cast<const bf16x8*>(kr + c * 32);
#pragma unroll
      for (int c2 = 0; c2 < 2; ++c2)
#pragma unroll
        for (int i = 0; i < 2; ++i)
          vpre[c2 * 2 + i] = *reinterpret_cast<const bf16x8*>(
              vb + (size_t)(i * 64 + sr) * T + kc2 + c2 * 32 + sc);
    }

#pragma unroll
    for (int t = 0; t < 2; ++t) {
      const int q0 = qt[t];
      if (kc > q0 + 15 || kc + 63 < q0 - W) continue;
      const int qr = q0 + lm;  // this lane's q row (softmax owner)

      f32x4 st[4] = {};
#pragma unroll
      for (int g = 0; g < 4; ++g)
#pragma unroll
        for (int c = 0; c < 4; ++c) {
          const bf16x8 kf =
              *reinterpret_cast<const bf16x8*>(&Ks[c][g * 16 + lm][quad * 8]);
          st[g] = __builtin_amdgcn_mfma_f32_16x16x32_bf16(kf, qf[t][c], st[g], 0, 0, 0);
        }
      float mx = -1e30f;
#pragma unroll
      for (int g = 0; g < 4; ++g)
#pragma unroll
        for (int r = 0; r < 4; ++r) {
          const int key = kc + g * 16 + quad * 4 + r;
          const bool valid = (key <= qr) && (qr - key <= W);
          st[g][r] = valid ? st[g][r] : -1e30f;
          mx = fmaxf(mx, st[g][r]);
        }
      mx = fmaxf(mx, __shfl_xor(mx, 16));
      mx = fmaxf(mx, __shfl_xor(mx, 32));
      const float mnew = fmaxf(mrun[t], mx);
      const float alpha = __builtin_amdgcn_exp2f(mrun[t] - mnew);
      mrun[t] = mnew;
      float rs = 0.f;
#pragma unroll
      for (int g = 0; g < 4; ++g) {
        bf16x4 pk;
#pragma unroll
        for (int r = 0; r < 4; ++r) {
          const float p = __builtin_amdgcn_exp2f(st[g][r] - mnew);
          rs += p;
          pk[r] = (bf16)p;
        }
        *reinterpret_cast<bf16x4*>(&Pb[wave][lm][g * 16 + quad * 4]) = pk;
      }
      rs += __shfl_xor(rs, 16);
      rs += __shfl_xor(rs, 32);
      lrun[t] = lrun[t] * alpha + rs;
#pragma unroll
      for (int dc = 0; dc < 8; ++dc)
#pragma unroll
        for (int r = 0; r < 4; ++r) oacc[t][dc][r] *= alpha;
#pragma unroll
      for (int c2 = 0; c2 < 2; ++c2) {
        const bf16x8 pf =
            *reinterpret_cast<const bf16x8*>(&Pb[wave][lm][c2 * 32 + quad * 8]);
#pragma unroll
        for (int dc = 0; dc < 8; ++dc) {
          const bf16x8 vf =
              *reinterpret_cast<const bf16x8*>(&Vs[c2][dc * 16 + lm][quad * 8]);
          oacc[t][dc] = __builtin_amdgcn_mfma_f32_16x16x32_bf16(vf, pf, oacc[t][dc], 0, 0, 0);
        }
      }
    }
  }

#pragma unroll
  for (int t = 0; t < 2; ++t) {
    const float inv = 1.f / lrun[t];
    bf16* yr = y + (size_t)(b * T + qt[t] + lm) * C + h * HEAD_DIM;
#pragma unroll
    for (int dc = 0; dc < 8; ++dc) {
      bf16x4 o;
#pragma unroll
      for (int r = 0; r < 4; ++r) o[r] = (bf16)(oacc[t][dc][r] * inv);
      *reinterpret_cast<bf16x4*>(yr + dc * 16 + quad * 4) = o;
    }
  }
}

extern "C" void kernel_launch(void* const* d_in, const int* in_sizes, int n_in,
                              void* d_out, int out_size, void* d_ws, size_t ws_size,
                              hipStream_t stream) {
  const float* x  = (const float*)d_in[0];
  const float* ve = (const float*)d_in[1];
  const float* Wq = (const float*)d_in[2];
  const float* Wk = (const float*)d_in[3];
  const float* Wv = (const float*)d_in[4];
  const float* Wp = (const float*)d_in[5];
  const float* Wg = (const float*)d_in[6];
  const float* cs = (const float*)d_in[7];
  const float* sn = (const float*)d_in[8];
  const int*   wl = (const int*)d_in[9];
  float* out = (float*)d_out;

  const int C = N_HEAD * HEAD_DIM;       // 2048
  const int T = in_sizes[7] / (HEAD_DIM / 2);
  const int B = in_sizes[0] / (T * C);
  const int M = B * T;

  bf16* xb   = (bf16*)d_ws;                    // [M][C]
  bf16* wqkv = xb   + (size_t)M * C;           // [3C][C] (Wq|Wk|Wv rows)
  bf16* wpb  = wqkv + (size_t)3 * C * C;       // [C][C]
  bf16* qkv  = wpb  + (size_t)C * C;           // [M][3C]
  bf16* ybuf = qkv  + (size_t)3 * M * C;       // [M][C]
  bf16* vTb  = xb;  // xb dead after QKV GEMM; reuse for V^T [B][H][128][T]

  const int nx4 = M * C / 4, nw4 = C * C / 4;
  cvt_all<<<dim3((nx4 + 255) / 256, 1, 5), 256, 0, stream>>>(
      x, Wq, Wk, Wv, Wp, xb, wqkv, wpb, nx4, nw4);

  // fused QKV: [M,3C] = xb[M,K] * wqkv[3C,K]^T — 256^2 8-phase kernel
  gemm256<<<dim3((3 * C / 256) * (M / 256)), 512, 0, stream>>>(
      xb, wqkv, qkv, M, 3 * C, C);

  rope_rms<<<dim3(M, N_HEAD / 4, 2), 256, 0, stream>>>(qkv, cs, sn, T);
  gate_transpose<<<dim3(T / 64, C / 64, B), 256, 0, stream>>>(qkv, x, ve, Wg, vTb, T);
  attn<<<dim3(B * N_HEAD * (T / 128)), 256, 0, stream>>>(qkv, vTb, ybuf, wl, T, B);

  gemm_bt<float><<<dim3(C / 128, M / 128), 256, 0, stream>>>(ybuf, wpb, out, M, C, C);
}

// Round 3
// 395.761 us; speedup vs baseline: 1.1006x; 1.0576x over previous
//
#include <hip/hip_runtime.h>
#include <hip/hip_bf16.h>
#include <cstdint>

#define N_HEAD 16
#define HEAD_DIM 128

typedef __bf16 bf16;
typedef __bf16 bf16x8 __attribute__((ext_vector_type(8)));
typedef __bf16 bf16x4 __attribute__((ext_vector_type(4)));
typedef float f32x4 __attribute__((ext_vector_type(4)));

// async global->LDS 16B (per-lane lds addr must be base + lane*16)
__device__ __forceinline__ void gload_lds16(const void* g, void* l) {
  auto gp = reinterpret_cast<const __attribute__((address_space(1))) char*>(
      reinterpret_cast<uintptr_t>(g));
  auto lp = reinterpret_cast<__attribute__((address_space(3))) char*>(
      reinterpret_cast<uintptr_t>(l));
  __builtin_amdgcn_global_load_lds(gp, lp, 16, 0, 0);
}

// ------- fp32 -> bf16 convert, all 5 tensors in one launch (z selects) ------
__global__ __launch_bounds__(256) void cvt_all(
    const float* __restrict__ x, const float* __restrict__ Wq,
    const float* __restrict__ Wk, const float* __restrict__ Wv,
    const float* __restrict__ Wp, bf16* __restrict__ xb,
    bf16* __restrict__ wqkv, bf16* __restrict__ wpb, int nx4, int nw4) {
  const int z = blockIdx.z;
  const float* in;
  bf16* out;
  int n4;
  if (z == 0)      { in = x;  out = xb;  n4 = nx4; }
  else if (z == 1) { in = Wq; out = wqkv;                     n4 = nw4; }
  else if (z == 2) { in = Wk; out = wqkv + (size_t)nw4 * 4;   n4 = nw4; }
  else if (z == 3) { in = Wv; out = wqkv + (size_t)nw4 * 8;   n4 = nw4; }
  else             { in = Wp; out = wpb;  n4 = nw4; }
  const int i = blockIdx.x * 256 + threadIdx.x;
  if (i >= n4) return;
  const float4 f = reinterpret_cast<const float4*>(in)[i];
  bf16x4 o;
  o.x = (bf16)f.x; o.y = (bf16)f.y; o.z = (bf16)f.z; o.w = (bf16)f.w;
  reinterpret_cast<bf16x4*>(out)[i] = o;
}

// ---------------- 256x256 8-phase GEMM (bf16 in/out) ------------------------
// BM=BN=256, BK=64, 512 threads (8 waves = 2Mx4N), per-wave C = 128x64.
// Verified round 2: bank-conflict 0, 57.8 us/block-round at K=2048.
// Grid supplies the tile count: nwg = gridDim.x (launch exactly (M/256)*NT
// blocks); B/C tile columns are bx*256 (dispatch covers N-cols [0, NT*256)).
__global__ __launch_bounds__(512, 2) void gemm256(
    const bf16* __restrict__ A, const bf16* __restrict__ Bt,
    bf16* __restrict__ C, int M, int N, int K) {
  __shared__ __align__(16) char sA[2][32768];
  __shared__ __align__(16) char sB[2][32768];

  const int nwgy = M >> 8;
  const int nwg = gridDim.x;
  const int q8 = nwg >> 3;
  const int wgid = (blockIdx.x & 7) * q8 + (blockIdx.x >> 3);
  const int by = wgid % nwgy;
  const int bx = wgid / nwgy;

  const int tid = threadIdx.x;
  const int lane = tid & 63;
  const int wave = tid >> 6;
  const int wm = (wave >> 2) << 7;   // 0 / 128
  const int wn = (wave & 3) << 6;    // 0..192
  const int lr = lane & 15;
  const int lk16 = (lane >> 4) << 4; // quad's 16B k-group
  const int sx = (lr & 7) << 4;      // read-side swizzle XOR (row&7)<<4

  const bf16* Ab = A + (size_t)by * 256 * K;
  const bf16* Bb = Bt + (size_t)bx * 256 * K;

  int srow[2], scol[2];
#pragma unroll
  for (int pp = 0; pp < 2; ++pp) {
    const int o = pp * 8192 + tid * 16;
    srow[pp] = o >> 7;
    scol[pp] = (o & 127) ^ ((srow[pp] & 7) << 4);
  }

  auto stageA = [&](int buf, int half, int k0) {
#pragma unroll
    for (int pp = 0; pp < 2; ++pp)
      gload_lds16(Ab + (size_t)(half * 128 + srow[pp]) * K + k0 + (scol[pp] >> 1),
                  sA[buf] + half * 16384 + pp * 8192 + tid * 16);
  };
  auto stageB = [&](int buf, int half, int k0) {
#pragma unroll
    for (int pp = 0; pp < 2; ++pp)
      gload_lds16(Bb + (size_t)(half * 128 + srow[pp]) * K + k0 + (scol[pp] >> 1),
                  sB[buf] + half * 16384 + pp * 8192 + tid * 16);
  };

  f32x4 acc[8][4] = {};
  bf16x8 bF[4][2];

#define VMCNT4                                             \
  asm volatile("s_waitcnt vmcnt(4)" ::: "memory");         \
  __builtin_amdgcn_sched_barrier(0)
#define VMCNT0                                             \
  asm volatile("s_waitcnt vmcnt(0)" ::: "memory");         \
  __builtin_amdgcn_sched_barrier(0)

#define PHASE(BUF, P, STAGE, WAIT)                                             \
  {                                                                            \
    bf16x8 aF[2][2];                                                           \
    if (P == 0) {                                                              \
      _Pragma("unroll") for (int n = 0; n < 4; ++n)                            \
      _Pragma("unroll") for (int ks = 0; ks < 2; ++ks)                         \
        bF[n][ks] = *reinterpret_cast<const bf16x8*>(                          \
            sB[BUF] + (wn + n * 16 + lr) * 128 + ((ks * 64 + lk16) ^ sx));     \
    }                                                                          \
    _Pragma("unroll") for (int mi = 0; mi < 2; ++mi)                           \
    _Pragma("unroll") for (int ks = 0; ks < 2; ++ks)                           \
      aF[mi][ks] = *reinterpret_cast<const bf16x8*>(                           \
          sA[BUF] + (wm + (P * 2 + mi) * 16 + lr) * 128 +                      \
          ((ks * 64 + lk16) ^ sx));                                            \
    STAGE;                                                                     \
    WAIT;                                                                      \
    __builtin_amdgcn_s_barrier();                                              \
    __builtin_amdgcn_s_setprio(1);                                             \
    _Pragma("unroll") for (int ks = 0; ks < 2; ++ks)                           \
    _Pragma("unroll") for (int mi = 0; mi < 2; ++mi)                           \
    _Pragma("unroll") for (int n = 0; n < 4; ++n)                              \
      acc[P * 2 + mi][n] = __builtin_amdgcn_mfma_f32_16x16x32_bf16(            \
          aF[mi][ks], bF[n][ks], acc[P * 2 + mi][n], 0, 0, 0);                 \
    __builtin_amdgcn_s_setprio(0);                                             \
    __builtin_amdgcn_s_barrier();                                              \
  }

  const int nIt = K >> 7;  // 2 K-steps (BK=64) per iteration

  stageB(0, 0, 0); stageB(0, 1, 0);
  stageA(0, 0, 0); stageA(0, 1, 0);
  stageB(1, 0, 64); stageB(1, 1, 64);
  VMCNT4;
  __builtin_amdgcn_s_barrier();

  int k0 = 0;
  for (int it = 0; it < nIt - 1; ++it, k0 += 128) {
    PHASE(0, 0, stageA(1, 0, k0 + 64), );
    PHASE(0, 1, stageA(1, 1, k0 + 64), );
    PHASE(0, 2, stageB(0, 0, k0 + 128), );
    PHASE(0, 3, stageB(0, 1, k0 + 128), VMCNT4);
    PHASE(1, 0, stageA(0, 0, k0 + 128), );
    PHASE(1, 1, stageA(0, 1, k0 + 128), );
    PHASE(1, 2, stageB(1, 0, k0 + 192), );
    PHASE(1, 3, stageB(1, 1, k0 + 192), VMCNT4);
  }
  PHASE(0, 0, stageA(1, 0, k0 + 64), );
  PHASE(0, 1, stageA(1, 1, k0 + 64), );
  PHASE(0, 2, , );
  PHASE(0, 3, , VMCNT0);
  PHASE(1, 0, , );
  PHASE(1, 1, , );
  PHASE(1, 2, , );
  PHASE(1, 3, , );
#undef PHASE
#undef VMCNT4
#undef VMCNT0

  const int orow = by * 256 + wm + (lane >> 4) * 4;
  const int ocol = bx * 256 + wn + lr;
#pragma unroll
  for (int m = 0; m < 8; ++m)
#pragma unroll
    for (int n = 0; n < 4; ++n)
#pragma unroll
      for (int r = 0; r < 4; ++r)
        C[(size_t)(orow + m * 16 + r) * N + (ocol + n * 16)] = (bf16)acc[m][n][r];
}

// ---------------- 128x256 8-phase GEMM (templated OutT) ---------------------
// BM=128, BN=256, BK=64, 512 threads (8 waves, 1Mx8N: per-wave C = 128x32).
// LDS 96 KiB (sA 2x16K, sB 2x32K). Deep stage/wait ledger: A staged as two
// 8-KiB halves (1 gload each), B as two 16-KiB halves (2 gloads each); every
// stage unit has a >=5-phase issue->wait window. Steady-state FIFO ledger
// (induction-verified): entry queue [1,2,3]=6; waits vmcnt(8)@p2 (covers p3's
// A-h1 reads), vmcnt(6)@p4 (covers p5's B+A-h0), vmcnt(8)@p6 (covers p7's
// A-h1), vmcnt(6)@p8 (covers next p1's B+A-h0). nOff = output-column offset
// (B rows nOff+bx*256). Grid = (M/128)*(Ncols_this_dispatch/256) blocks.
template <typename OutT>
__global__ __launch_bounds__(512, 2) void gemm128(
    const bf16* __restrict__ A, const bf16* __restrict__ Bt,
    OutT* __restrict__ C, int M, int Ncols, int K, int nOff) {
  __shared__ __align__(16) char sA[2][16384];
  __shared__ __align__(16) char sB[2][32768];

  const int nwgy = M >> 7;
  const int nwg = gridDim.x;
  const int q8 = nwg >> 3;
  const int wgid = (blockIdx.x & 7) * q8 + (blockIdx.x >> 3);
  const int by = wgid % nwgy;
  const int bx = wgid / nwgy;

  const int tid = threadIdx.x;
  const int lane = tid & 63;
  const int wave = tid >> 6;
  const int wn = wave << 5;          // 0..224
  const int lr = lane & 15;
  const int lk16 = (lane >> 4) << 4;
  const int sx = (lr & 7) << 4;

  const bf16* Ab = A + (size_t)by * 128 * K;
  const bf16* Bb = Bt + (size_t)(nOff + bx * 256) * K;

  int srow[2], scol[2];
#pragma unroll
  for (int pp = 0; pp < 2; ++pp) {
    const int o = pp * 8192 + tid * 16;
    srow[pp] = o >> 7;
    scol[pp] = (o & 127) ^ ((srow[pp] & 7) << 4);
  }

  // B half: 16 KiB = rows half*128..half*128+127, 2 gloads
  auto stageB = [&](int buf, int half, int k0) {
#pragma unroll
    for (int pp = 0; pp < 2; ++pp)
      gload_lds16(Bb + (size_t)(half * 128 + srow[pp]) * K + k0 + (scol[pp] >> 1),
                  sB[buf] + half * 16384 + pp * 8192 + tid * 16);
  };
  // A half: 8 KiB = rows half*64..half*64+63, 1 gload
  auto stageA = [&](int buf, int half, int k0) {
    const int o = tid * 16;
    const int row = o >> 7;  // 0..63
    const int col = (o & 127) ^ ((row & 7) << 4);
    gload_lds16(Ab + (size_t)(half * 64 + row) * K + k0 + (col >> 1),
                sA[buf] + half * 8192 + o);
  };

  f32x4 acc[8][2] = {};
  bf16x8 bF[2][2];

#define WAITV(n)                                               \
  asm volatile("s_waitcnt vmcnt(" #n ")" ::: "memory");        \
  __builtin_amdgcn_sched_barrier(0)

#define PH128(BUF, P, STAGE, WAIT)                                             \
  {                                                                            \
    bf16x8 aF[2][2];                                                           \
    if (P == 0) {                                                              \
      _Pragma("unroll") for (int n = 0; n < 2; ++n)                            \
      _Pragma("unroll") for (int ks = 0; ks < 2; ++ks)                         \
        bF[n][ks] = *reinterpret_cast<const bf16x8*>(                          \
            sB[BUF] + (wn + n * 16 + lr) * 128 + ((ks * 64 + lk16) ^ sx));     \
    }                                                                          \
    _Pragma("unroll") for (int mi = 0; mi < 2; ++mi)                           \
    _Pragma("unroll") for (int ks = 0; ks < 2; ++ks)                           \
      aF[mi][ks] = *reinterpret_cast<const bf16x8*>(                           \
          sA[BUF] + ((P * 2 + mi) * 16 + lr) * 128 + ((ks * 64 + lk16) ^ sx)); \
    STAGE;                                                                     \
    WAIT;                                                                      \
    __builtin_amdgcn_s_barrier();                                              \
    __builtin_amdgcn_s_setprio(1);                                             \
    _Pragma("unroll") for (int ks = 0; ks < 2; ++ks)                           \
    _Pragma("unroll") for (int mi = 0; mi < 2; ++mi)                           \
    _Pragma("unroll") for (int n = 0; n < 2; ++n)                              \
      acc[P * 2 + mi][n] = __builtin_amdgcn_mfma_f32_16x16x32_bf16(            \
          aF[mi][ks], bF[n][ks], acc[P * 2 + mi][n], 0, 0, 0);                 \
    __builtin_amdgcn_s_setprio(0);                                             \
    __builtin_amdgcn_s_barrier();                                              \
  }

  const int nIt = K >> 7;

  // prologue: buf0 full (6 loads), buf1 B + A-h0 (5 loads); drain buf0.
  stageB(0, 0, 0); stageB(0, 1, 0);
  stageA(0, 0, 0); stageA(0, 1, 0);
  stageB(1, 0, 64); stageB(1, 1, 64);
  stageA(1, 0, 64);
  WAITV(5);
  __builtin_amdgcn_s_barrier();

  int k0 = 0;
  for (int it = 0; it < nIt - 1; ++it, k0 += 128) {
    PH128(0, 0, stageA(1, 1, k0 + 64), );                               // p1
    PH128(0, 1, stageB(0, 0, k0 + 128), WAITV(8));                      // p2
    PH128(0, 2, (stageB(0, 1, k0 + 128), stageA(0, 0, k0 + 128)), );    // p3
    PH128(0, 3, , WAITV(6));                                            // p4
    PH128(1, 0, stageA(0, 1, k0 + 128), );                              // p5
    PH128(1, 1, stageB(1, 0, k0 + 192), WAITV(8));                      // p6
    PH128(1, 2, (stageB(1, 1, k0 + 192), stageA(1, 0, k0 + 192)), );    // p7
    PH128(1, 3, , WAITV(6));                                            // p8
  }
  // final iteration: only buf1.A-h1 still needs staging
  PH128(0, 0, stageA(1, 1, k0 + 64), );
  PH128(0, 1, , WAITV(6));
  PH128(0, 2, , );
  PH128(0, 3, , WAITV(1));
  PH128(1, 0, , );
  PH128(1, 1, , WAITV(0));
  PH128(1, 2, , );
  PH128(1, 3, , );
#undef PH128
#undef WAITV

  const int orow = by * 128 + (lane >> 4) * 4;
  const int ocol = nOff + bx * 256 + wn + lr;
#pragma unroll
  for (int m = 0; m < 8; ++m)
#pragma unroll
    for (int n = 0; n < 2; ++n)
#pragma unroll
      for (int r = 0; r < 4; ++r)
        C[(size_t)(orow + m * 16 + r) * Ncols + (ocol + n * 16)] = (OutT)acc[m][n][r];
}

// ---------------- rope + rms-norm, in-place on q,k inside qkv buffer --------
__global__ __launch_bounds__(256) void rope_rms(
    bf16* __restrict__ qkv, const float* __restrict__ cs,
    const float* __restrict__ sn, int T) {
  const int C = N_HEAD * HEAD_DIM;
  const int S = 3 * C;
  const int bt = blockIdx.x;
  const int t = bt % T;
  const int wave = threadIdx.x >> 6;
  const int lane = threadIdx.x & 63;
  const int h = blockIdx.y * 4 + wave;
  bf16* p = qkv + (size_t)bt * S + (blockIdx.z ? C : 0) + h * HEAD_DIM;
  // q: 1.2 * 0.08838834764831845 * 1.4426950408889634 (exp2-domain softmax)
  const float oscale = blockIdx.z ? 1.2f : 0.15302091809294977f;
  const float c = cs[t * 64 + lane];
  const float s = sn[t * 64 + lane];
  const float x1 = (float)p[lane];
  const float x2 = (float)p[lane + 64];
  const float r1 = x1 * c + x2 * s;
  const float r2 = x2 * c - x1 * s;
  float ss = r1 * r1 + r2 * r2;
#pragma unroll
  for (int m = 1; m < 64; m <<= 1) ss += __shfl_xor(ss, m);
  const float sc = oscale * rsqrtf(ss * (1.0f / 128.0f) + 1e-6f);
  p[lane] = (bf16)(r1 * sc);
  p[lane + 64] = (bf16)(r2 * sc);
}

// ---------------- gate + transpose: vT[b][h][d][t] = v[b][t][h][d] + gate*ve --
__global__ __launch_bounds__(256) void gate_transpose(
    const bf16* __restrict__ qkv, const float* __restrict__ x,
    const float* __restrict__ ve, const float* __restrict__ Wg,
    bf16* __restrict__ vT, int T) {
  const int C = N_HEAD * HEAD_DIM;
  const int S = 3 * C;
  const int t0 = blockIdx.x * 64;
  const int c0 = blockIdx.y * 64;
  const int b = blockIdx.z;
  const int h = c0 >> 7;

  __shared__ float gs[64];
  __shared__ __align__(16) bf16 tile[64][72];

  if (threadIdx.x < 64) {
    const float* xr = x + (size_t)(b * T + t0 + threadIdx.x) * C;
    float a = 0.f;
#pragma unroll
    for (int j = 0; j < 12; ++j) a += xr[j] * Wg[h * 12 + j];
    gs[threadIdx.x] = 3.f / (1.f + __expf(-a));
  }
  __syncthreads();

  {
    const int r = threadIdx.x >> 2;
    const int cc = (threadIdx.x & 3) * 16;
    const size_t vrow = (size_t)(b * T + t0 + r) * S + 2 * C + c0 + cc;
    const size_t erow = (size_t)(b * T + t0 + r) * C + c0 + cc;
    bf16x8 a0 = *reinterpret_cast<const bf16x8*>(qkv + vrow);
    bf16x8 a1 = *reinterpret_cast<const bf16x8*>(qkv + vrow + 8);
    const float g = gs[r];
    bf16x8 o0, o1;
#pragma unroll
    for (int i = 0; i < 8; ++i) o0[i] = (bf16)((float)a0[i] + g * ve[erow + i]);
#pragma unroll
    for (int i = 0; i < 8; ++i) o1[i] = (bf16)((float)a1[i] + g * ve[erow + 8 + i]);
    *reinterpret_cast<bf16x8*>(&tile[r][cc]) = o0;
    *reinterpret_cast<bf16x8*>(&tile[r][cc + 8]) = o1;
  }
  __syncthreads();
  {
    const int dr = threadIdx.x >> 2;        // col of tile = d offset
    const int tc = (threadIdx.x & 3) * 16;  // row of tile = t offset
    bf16x8 o0, o1;
#pragma unroll
    for (int i = 0; i < 8; ++i) o0[i] = tile[tc + i][dr];
#pragma unroll
    for (int i = 0; i < 8; ++i) o1[i] = tile[tc + 8 + i][dr];
    const size_t orow =
        ((size_t)((b * N_HEAD + h) * HEAD_DIM) + (c0 & 127) + dr) * T + t0 + tc;
    *reinterpret_cast<bf16x8*>(vT + orow) = o0;
    *reinterpret_cast<bf16x8*>(vT + orow + 8) = o1;
  }
}

// ---------------- flash attention, sliding window, LDS-staged --------------
__global__ __launch_bounds__(256, 2) void attn(
    const bf16* __restrict__ qkv, const bf16* __restrict__ vT,
    bf16* __restrict__ y, const int* __restrict__ wptr, int T, int B) {
  const int C = N_HEAD * HEAD_DIM;
  const int S = 3 * C;
  const int nq = T >> 7;                       // q-blocks per (b,h)
  const int ppx = (B * N_HEAD) >> 3;           // (b,h) pairs per XCD
  const int bid = blockIdx.x;
  const int xcd = bid & 7;
  const int sl = bid >> 3;
  const int pair = xcd * ppx + sl / nq;
  const int qi = sl % nq;
  const int b = pair / N_HEAD;
  const int h = pair % N_HEAD;
  const int qb = qi * 128;

  const int tid = threadIdx.x;
  const int wave = tid >> 6;
  const int lane = tid & 63;
  const int lm = lane & 15;
  const int quad = lane >> 4;

  const int w = wptr[0];
  const int W = (w > 0 && w < T) ? w : (1 << 30);

  __shared__ __align__(16) bf16 Ks[4][64][32];   // [d-chunk][key][32]  16 KB
  __shared__ __align__(16) bf16 Vs[2][128][32];  // [key-chunk][d][32]  16 KB
  __shared__ __align__(16) bf16 Pb[4][16][72];   // per-wave P[q][64key]  9 KB

  const bf16* kb = qkv + (size_t)b * T * S + C + (size_t)h * HEAD_DIM;
  const bf16* vb = vT + (size_t)((b * N_HEAD + h) * HEAD_DIM) * T;  // [128][T]

  const int qt[2] = {qb + wave * 16, qb + 64 + wave * 16};
  bf16x8 qf[2][4];
#pragma unroll
  for (int t = 0; t < 2; ++t) {
    const bf16* qrow = qkv + (size_t)(b * T + qt[t] + lm) * S + h * HEAD_DIM;
#pragma unroll
    for (int c = 0; c < 4; ++c)
      qf[t][c] = *reinterpret_cast<const bf16x8*>(qrow + c * 32 + quad * 8);
  }

  float mrun[2] = {-1e30f, -1e30f}, lrun[2] = {0.f, 0.f};
  f32x4 oacc[2][8] = {};

  int kstart = qb - W;
  if (kstart < 0) kstart = 0;
  kstart &= ~63;
  const int kend = qb + 64;  // last chunk start

  const int sr = tid >> 2;       // staging row 0..63
  const int sc = (tid & 3) * 8;  // staging col offset (elements)

  bf16x8 kpre[4], vpre[4];
  {
    const bf16* kr = kb + (size_t)(kstart + sr) * S + sc;
#pragma unroll
    for (int c = 0; c < 4; ++c)
      kpre[c] = *reinterpret_cast<const bf16x8*>(kr + c * 32);
#pragma unroll
    for (int c2 = 0; c2 < 2; ++c2)
#pragma unroll
      for (int i = 0; i < 2; ++i)
        vpre[c2 * 2 + i] = *reinterpret_cast<const bf16x8*>(
            vb + (size_t)(i * 64 + sr) * T + kstart + c2 * 32 + sc);
  }

  for (int kc = kstart; kc <= kend; kc += 64) {
    __syncthreads();
#pragma unroll
    for (int c = 0; c < 4; ++c)
      *reinterpret_cast<bf16x8*>(&Ks[c][sr][sc]) = kpre[c];
#pragma unroll
    for (int c2 = 0; c2 < 2; ++c2)
#pragma unroll
      for (int i = 0; i < 2; ++i)
        *reinterpret_cast<bf16x8*>(&Vs[c2][i * 64 + sr][sc]) = vpre[c2 * 2 + i];
    __syncthreads();

    if (kc + 64 <= kend) {
      const int kc2 = kc + 64;
      const bf16* kr = kb + (size_t)(kc2 + sr) * S + sc;
#pragma unroll
      for (int c = 0; c < 4; ++c)
        kpre[c] = *reinterpret_cast<const bf16x8*>(kr + c * 32);
#pragma unroll
      for (int c2 = 0; c2 < 2; ++c2)
#pragma unroll
        for (int i = 0; i < 2; ++i)
          vpre[c2 * 2 + i] = *reinterpret_cast<const bf16x8*>(
              vb + (size_t)(i * 64 + sr) * T + kc2 + c2 * 32 + sc);
    }

#pragma unroll
    for (int t = 0; t < 2; ++t) {
      const int q0 = qt[t];
      if (kc > q0 + 15 || kc + 63 < q0 - W) continue;
      const int qr = q0 + lm;  // this lane's q row (softmax owner)

      f32x4 st[4] = {};
#pragma unroll
      for (int g = 0; g < 4; ++g)
#pragma unroll
        for (int c = 0; c < 4; ++c) {
          const bf16x8 kf =
              *reinterpret_cast<const bf16x8*>(&Ks[c][g * 16 + lm][quad * 8]);
          st[g] = __builtin_amdgcn_mfma_f32_16x16x32_bf16(kf, qf[t][c], st[g], 0, 0, 0);
        }
      float mx = -1e30f;
#pragma unroll
      for (int g = 0; g < 4; ++g)
#pragma unroll
        for (int r = 0; r < 4; ++r) {
          const int key = kc + g * 16 + quad * 4 + r;
          const bool valid = (key <= qr) && (qr - key <= W);
          st[g][r] = valid ? st[g][r] : -1e30f;
          mx = fmaxf(mx, st[g][r]);
        }
      mx = fmaxf(mx, __shfl_xor(mx, 16));
      mx = fmaxf(mx, __shfl_xor(mx, 32));
      const float mnew = fmaxf(mrun[t], mx);
      const float alpha = __builtin_amdgcn_exp2f(mrun[t] - mnew);
      mrun[t] = mnew;
      float rs = 0.f;
#pragma unroll
      for (int g = 0; g < 4; ++g) {
        bf16x4 pk;
#pragma unroll
        for (int r = 0; r < 4; ++r) {
          const float p = __builtin_amdgcn_exp2f(st[g][r] - mnew);
          rs += p;
          pk[r] = (bf16)p;
        }
        *reinterpret_cast<bf16x4*>(&Pb[wave][lm][g * 16 + quad * 4]) = pk;
      }
      rs += __shfl_xor(rs, 16);
      rs += __shfl_xor(rs, 32);
      lrun[t] = lrun[t] * alpha + rs;
#pragma unroll
      for (int dc = 0; dc < 8; ++dc)
#pragma unroll
        for (int r = 0; r < 4; ++r) oacc[t][dc][r] *= alpha;
#pragma unroll
      for (int c2 = 0; c2 < 2; ++c2) {
        const bf16x8 pf =
            *reinterpret_cast<const bf16x8*>(&Pb[wave][lm][c2 * 32 + quad * 8]);
#pragma unroll
        for (int dc = 0; dc < 8; ++dc) {
          const bf16x8 vf =
              *reinterpret_cast<const bf16x8*>(&Vs[c2][dc * 16 + lm][quad * 8]);
          oacc[t][dc] = __builtin_amdgcn_mfma_f32_16x16x32_bf16(vf, pf, oacc[t][dc], 0, 0, 0);
        }
      }
    }
  }

#pragma unroll
  for (int t = 0; t < 2; ++t) {
    const float inv = 1.f / lrun[t];
    bf16* yr = y + (size_t)(b * T + qt[t] + lm) * C + h * HEAD_DIM;
#pragma unroll
    for (int dc = 0; dc < 8; ++dc) {
      bf16x4 o;
#pragma unroll
      for (int r = 0; r < 4; ++r) o[r] = (bf16)(oacc[t][dc][r] * inv);
      *reinterpret_cast<bf16x4*>(yr + dc * 16 + quad * 4) = o;
    }
  }
}

extern "C" void kernel_launch(void* const* d_in, const int* in_sizes, int n_in,
                              void* d_out, int out_size, void* d_ws, size_t ws_size,
                              hipStream_t stream) {
  const float* x  = (const float*)d_in[0];
  const float* ve = (const float*)d_in[1];
  const float* Wq = (const float*)d_in[2];
  const float* Wk = (const float*)d_in[3];
  const float* Wv = (const float*)d_in[4];
  const float* Wp = (const float*)d_in[5];
  const float* Wg = (const float*)d_in[6];
  const float* cs = (const float*)d_in[7];
  const float* sn = (const float*)d_in[8];
  const int*   wl = (const int*)d_in[9];
  float* out = (float*)d_out;

  const int C = N_HEAD * HEAD_DIM;       // 2048
  const int T = in_sizes[7] / (HEAD_DIM / 2);
  const int B = in_sizes[0] / (T * C);
  const int M = B * T;

  bf16* xb   = (bf16*)d_ws;                    // [M][C]
  bf16* wqkv = xb   + (size_t)M * C;           // [3C][C] (Wq|Wk|Wv rows)
  bf16* wpb  = wqkv + (size_t)3 * C * C;       // [C][C]
  bf16* qkv  = wpb  + (size_t)C * C;           // [M][3C]
  bf16* ybuf = qkv  + (size_t)3 * M * C;       // [M][C]
  bf16* vTb  = xb;  // xb dead after QKV GEMM; reuse for V^T [B][H][128][T]

  const int nx4 = M * C / 4, nw4 = C * C / 4;
  cvt_all<<<dim3((nx4 + 255) / 256, 1, 5), 256, 0, stream>>>(
      x, Wq, Wk, Wv, Wp, xb, wqkv, wpb, nx4, nw4);

  // QKV split for exact-round grids (256 CUs, 1 block/CU):
  // part 1: Q|K cols 0..4095  -> gemm256, (4096/256)*(4096/256) = 256 blocks
  // part 2: V  cols 4096..6143 -> gemm128, (4096/128)*(2048/256) = 256 blocks
  gemm256<<<dim3((M / 256) * 16), 512, 0, stream>>>(xb, wqkv, qkv, M, 3 * C, C);
  gemm128<bf16><<<dim3((M / 128) * 8), 512, 0, stream>>>(
      xb, wqkv, qkv, M, 3 * C, C, 2 * C);

  rope_rms<<<dim3(M, N_HEAD / 4, 2), 256, 0, stream>>>(qkv, cs, sn, T);
  gate_transpose<<<dim3(T / 64, C / 64, B), 256, 0, stream>>>(qkv, x, ve, Wg, vTb, T);
  attn<<<dim3(B * N_HEAD * (T / 128)), 256, 0, stream>>>(qkv, vTb, ybuf, wl, T, B);

  // projection: [M,2048] = ybuf * wpb^T -> gemm128<float>, 32*8 = 256 blocks
  gemm128<float><<<dim3((M / 128) * (C / 256)), 512, 0, stream>>>(
      ybuf, wpb, out, M, C, C, 0);
}

// Round 4
// 390.809 us; speedup vs baseline: 1.1145x; 1.0127x over previous
//
#include <hip/hip_runtime.h>
#include <hip/hip_bf16.h>
#include <cstdint>

#define N_HEAD 16
#define HEAD_DIM 128

typedef __bf16 bf16;
typedef __bf16 bf16x8 __attribute__((ext_vector_type(8)));
typedef __bf16 bf16x4 __attribute__((ext_vector_type(4)));
typedef float f32x4 __attribute__((ext_vector_type(4)));

// async global->LDS 16B (per-lane lds addr must be base + lane*16)
__device__ __forceinline__ void gload_lds16(const void* g, void* l) {
  auto gp = reinterpret_cast<const __attribute__((address_space(1))) char*>(
      reinterpret_cast<uintptr_t>(g));
  auto lp = reinterpret_cast<__attribute__((address_space(3))) char*>(
      reinterpret_cast<uintptr_t>(l));
  __builtin_amdgcn_global_load_lds(gp, lp, 16, 0, 0);
}

// ------- fp32 -> bf16 convert, all 5 tensors in one launch (z selects) ------
__global__ __launch_bounds__(256) void cvt_all(
    const float* __restrict__ x, const float* __restrict__ Wq,
    const float* __restrict__ Wk, const float* __restrict__ Wv,
    const float* __restrict__ Wp, bf16* __restrict__ xb,
    bf16* __restrict__ wqkv, bf16* __restrict__ wpb, int nx4, int nw4) {
  const int z = blockIdx.z;
  const float* in;
  bf16* out;
  int n4;
  if (z == 0)      { in = x;  out = xb;  n4 = nx4; }
  else if (z == 1) { in = Wq; out = wqkv;                     n4 = nw4; }
  else if (z == 2) { in = Wk; out = wqkv + (size_t)nw4 * 4;   n4 = nw4; }
  else if (z == 3) { in = Wv; out = wqkv + (size_t)nw4 * 8;   n4 = nw4; }
  else             { in = Wp; out = wpb;  n4 = nw4; }
  const int i = blockIdx.x * 256 + threadIdx.x;
  if (i >= n4) return;
  const float4 f = reinterpret_cast<const float4*>(in)[i];
  bf16x4 o;
  o.x = (bf16)f.x; o.y = (bf16)f.y; o.z = (bf16)f.z; o.w = (bf16)f.w;
  reinterpret_cast<bf16x4*>(out)[i] = o;
}

// ---------------- 256x256 8-phase GEMM (bf16 in/out) ------------------------
// BM=BN=256, BK=64, 512 threads (8 waves = 2Mx4N), per-wave C = 128x64.
// Verified round 2: bank-conflict 0. Grid = (M/256)*NT blocks, NT columns.
__global__ __launch_bounds__(512, 2) void gemm256(
    const bf16* __restrict__ A, const bf16* __restrict__ Bt,
    bf16* __restrict__ C, int M, int N, int K) {
  __shared__ __align__(16) char sA[2][32768];
  __shared__ __align__(16) char sB[2][32768];

  const int nwgy = M >> 8;
  const int nwg = gridDim.x;
  const int q8 = nwg >> 3;
  const int wgid = (blockIdx.x & 7) * q8 + (blockIdx.x >> 3);
  const int by = wgid % nwgy;
  const int bx = wgid / nwgy;

  const int tid = threadIdx.x;
  const int lane = tid & 63;
  const int wave = tid >> 6;
  const int wm = (wave >> 2) << 7;   // 0 / 128
  const int wn = (wave & 3) << 6;    // 0..192
  const int lr = lane & 15;
  const int lk16 = (lane >> 4) << 4; // quad's 16B k-group
  const int sx = (lr & 7) << 4;      // read-side swizzle XOR (row&7)<<4

  const bf16* Ab = A + (size_t)by * 256 * K;
  const bf16* Bb = Bt + (size_t)bx * 256 * K;

  int srow[2], scol[2];
#pragma unroll
  for (int pp = 0; pp < 2; ++pp) {
    const int o = pp * 8192 + tid * 16;
    srow[pp] = o >> 7;
    scol[pp] = (o & 127) ^ ((srow[pp] & 7) << 4);
  }

  auto stageA = [&](int buf, int half, int k0) {
#pragma unroll
    for (int pp = 0; pp < 2; ++pp)
      gload_lds16(Ab + (size_t)(half * 128 + srow[pp]) * K + k0 + (scol[pp] >> 1),
                  sA[buf] + half * 16384 + pp * 8192 + tid * 16);
  };
  auto stageB = [&](int buf, int half, int k0) {
#pragma unroll
    for (int pp = 0; pp < 2; ++pp)
      gload_lds16(Bb + (size_t)(half * 128 + srow[pp]) * K + k0 + (scol[pp] >> 1),
                  sB[buf] + half * 16384 + pp * 8192 + tid * 16);
  };

  f32x4 acc[8][4] = {};
  bf16x8 bF[4][2];

#define VMCNT4                                             \
  asm volatile("s_waitcnt vmcnt(4)" ::: "memory");         \
  __builtin_amdgcn_sched_barrier(0)
#define VMCNT0                                             \
  asm volatile("s_waitcnt vmcnt(0)" ::: "memory");         \
  __builtin_amdgcn_sched_barrier(0)

#define PHASE(BUF, P, STAGE, WAIT)                                             \
  {                                                                            \
    bf16x8 aF[2][2];                                                           \
    if (P == 0) {                                                              \
      _Pragma("unroll") for (int n = 0; n < 4; ++n)                            \
      _Pragma("unroll") for (int ks = 0; ks < 2; ++ks)                         \
        bF[n][ks] = *reinterpret_cast<const bf16x8*>(                          \
            sB[BUF] + (wn + n * 16 + lr) * 128 + ((ks * 64 + lk16) ^ sx));     \
    }                                                                          \
    _Pragma("unroll") for (int mi = 0; mi < 2; ++mi)                           \
    _Pragma("unroll") for (int ks = 0; ks < 2; ++ks)                           \
      aF[mi][ks] = *reinterpret_cast<const bf16x8*>(                           \
          sA[BUF] + (wm + (P * 2 + mi) * 16 + lr) * 128 +                      \
          ((ks * 64 + lk16) ^ sx));                                            \
    STAGE;                                                                     \
    WAIT;                                                                      \
    __builtin_amdgcn_s_barrier();                                              \
    __builtin_amdgcn_s_setprio(1);                                             \
    _Pragma("unroll") for (int ks = 0; ks < 2; ++ks)                           \
    _Pragma("unroll") for (int mi = 0; mi < 2; ++mi)                           \
    _Pragma("unroll") for (int n = 0; n < 4; ++n)                              \
      acc[P * 2 + mi][n] = __builtin_amdgcn_mfma_f32_16x16x32_bf16(            \
          aF[mi][ks], bF[n][ks], acc[P * 2 + mi][n], 0, 0, 0);                 \
    __builtin_amdgcn_s_setprio(0);                                             \
    __builtin_amdgcn_s_barrier();                                              \
  }

  const int nIt = K >> 7;  // 2 K-steps (BK=64) per iteration

  stageB(0, 0, 0); stageB(0, 1, 0);
  stageA(0, 0, 0); stageA(0, 1, 0);
  stageB(1, 0, 64); stageB(1, 1, 64);
  VMCNT4;
  __builtin_amdgcn_s_barrier();

  int k0 = 0;
  for (int it = 0; it < nIt - 1; ++it, k0 += 128) {
    PHASE(0, 0, stageA(1, 0, k0 + 64), );
    PHASE(0, 1, stageA(1, 1, k0 + 64), );
    PHASE(0, 2, stageB(0, 0, k0 + 128), );
    PHASE(0, 3, stageB(0, 1, k0 + 128), VMCNT4);
    PHASE(1, 0, stageA(0, 0, k0 + 128), );
    PHASE(1, 1, stageA(0, 1, k0 + 128), );
    PHASE(1, 2, stageB(1, 0, k0 + 192), );
    PHASE(1, 3, stageB(1, 1, k0 + 192), VMCNT4);
  }
  PHASE(0, 0, stageA(1, 0, k0 + 64), );
  PHASE(0, 1, stageA(1, 1, k0 + 64), );
  PHASE(0, 2, , );
  PHASE(0, 3, , VMCNT0);
  PHASE(1, 0, , );
  PHASE(1, 1, , );
  PHASE(1, 2, , );
  PHASE(1, 3, , );
#undef PHASE
#undef VMCNT4
#undef VMCNT0

  const int orow = by * 256 + wm + (lane >> 4) * 4;
  const int ocol = bx * 256 + wn + lr;
#pragma unroll
  for (int m = 0; m < 8; ++m)
#pragma unroll
    for (int n = 0; n < 4; ++n)
#pragma unroll
      for (int r = 0; r < 4; ++r)
        C[(size_t)(orow + m * 16 + r) * N + (ocol + n * 16)] = (bf16)acc[m][n][r];
}

// ---------------- 128x256 8-phase GEMM (templated OutT) ---------------------
// BM=128, BN=256, BK=64, 512 threads (8 waves, 1Mx8N: per-wave C = 128x32).
// LDS 96 KiB. Deep stage/wait ledger (verified round 3).
template <typename OutT>
__global__ __launch_bounds__(512, 2) void gemm128(
    const bf16* __restrict__ A, const bf16* __restrict__ Bt,
    OutT* __restrict__ C, int M, int Ncols, int K, int nOff) {
  __shared__ __align__(16) char sA[2][16384];
  __shared__ __align__(16) char sB[2][32768];

  const int nwgy = M >> 7;
  const int nwg = gridDim.x;
  const int q8 = nwg >> 3;
  const int wgid = (blockIdx.x & 7) * q8 + (blockIdx.x >> 3);
  const int by = wgid % nwgy;
  const int bx = wgid / nwgy;

  const int tid = threadIdx.x;
  const int lane = tid & 63;
  const int wave = tid >> 6;
  const int wn = wave << 5;          // 0..224
  const int lr = lane & 15;
  const int lk16 = (lane >> 4) << 4;
  const int sx = (lr & 7) << 4;

  const bf16* Ab = A + (size_t)by * 128 * K;
  const bf16* Bb = Bt + (size_t)(nOff + bx * 256) * K;

  int srow[2], scol[2];
#pragma unroll
  for (int pp = 0; pp < 2; ++pp) {
    const int o = pp * 8192 + tid * 16;
    srow[pp] = o >> 7;
    scol[pp] = (o & 127) ^ ((srow[pp] & 7) << 4);
  }

  auto stageB = [&](int buf, int half, int k0) {
#pragma unroll
    for (int pp = 0; pp < 2; ++pp)
      gload_lds16(Bb + (size_t)(half * 128 + srow[pp]) * K + k0 + (scol[pp] >> 1),
                  sB[buf] + half * 16384 + pp * 8192 + tid * 16);
  };
  auto stageA = [&](int buf, int half, int k0) {
    const int o = tid * 16;
    const int row = o >> 7;  // 0..63
    const int col = (o & 127) ^ ((row & 7) << 4);
    gload_lds16(Ab + (size_t)(half * 64 + row) * K + k0 + (col >> 1),
                sA[buf] + half * 8192 + o);
  };

  f32x4 acc[8][2] = {};
  bf16x8 bF[2][2];

#define WAITV(n)                                               \
  asm volatile("s_waitcnt vmcnt(" #n ")" ::: "memory");        \
  __builtin_amdgcn_sched_barrier(0)

#define PH128(BUF, P, STAGE, WAIT)                                             \
  {                                                                            \
    bf16x8 aF[2][2];                                                           \
    if (P == 0) {                                                              \
      _Pragma("unroll") for (int n = 0; n < 2; ++n)                            \
      _Pragma("unroll") for (int ks = 0; ks < 2; ++ks)                         \
        bF[n][ks] = *reinterpret_cast<const bf16x8*>(                          \
            sB[BUF] + (wn + n * 16 + lr) * 128 + ((ks * 64 + lk16) ^ sx));     \
    }                                                                          \
    _Pragma("unroll") for (int mi = 0; mi < 2; ++mi)                           \
    _Pragma("unroll") for (int ks = 0; ks < 2; ++ks)                           \
      aF[mi][ks] = *reinterpret_cast<const bf16x8*>(                           \
          sA[BUF] + ((P * 2 + mi) * 16 + lr) * 128 + ((ks * 64 + lk16) ^ sx)); \
    STAGE;                                                                     \
    WAIT;                                                                      \
    __builtin_amdgcn_s_barrier();                                              \
    __builtin_amdgcn_s_setprio(1);                                             \
    _Pragma("unroll") for (int ks = 0; ks < 2; ++ks)                           \
    _Pragma("unroll") for (int mi = 0; mi < 2; ++mi)                           \
    _Pragma("unroll") for (int n = 0; n < 2; ++n)                              \
      acc[P * 2 + mi][n] = __builtin_amdgcn_mfma_f32_16x16x32_bf16(            \
          aF[mi][ks], bF[n][ks], acc[P * 2 + mi][n], 0, 0, 0);                 \
    __builtin_amdgcn_s_setprio(0);                                             \
    __builtin_amdgcn_s_barrier();                                              \
  }

  const int nIt = K >> 7;

  stageB(0, 0, 0); stageB(0, 1, 0);
  stageA(0, 0, 0); stageA(0, 1, 0);
  stageB(1, 0, 64); stageB(1, 1, 64);
  stageA(1, 0, 64);
  WAITV(5);
  __builtin_amdgcn_s_barrier();

  int k0 = 0;
  for (int it = 0; it < nIt - 1; ++it, k0 += 128) {
    PH128(0, 0, stageA(1, 1, k0 + 64), );                               // p1
    PH128(0, 1, stageB(0, 0, k0 + 128), WAITV(8));                      // p2
    PH128(0, 2, (stageB(0, 1, k0 + 128), stageA(0, 0, k0 + 128)), );    // p3
    PH128(0, 3, , WAITV(6));                                            // p4
    PH128(1, 0, stageA(0, 1, k0 + 128), );                              // p5
    PH128(1, 1, stageB(1, 0, k0 + 192), WAITV(8));                      // p6
    PH128(1, 2, (stageB(1, 1, k0 + 192), stageA(1, 0, k0 + 192)), );    // p7
    PH128(1, 3, , WAITV(6));                                            // p8
  }
  PH128(0, 0, stageA(1, 1, k0 + 64), );
  PH128(0, 1, , WAITV(6));
  PH128(0, 2, , );
  PH128(0, 3, , WAITV(1));
  PH128(1, 0, , );
  PH128(1, 1, , WAITV(0));
  PH128(1, 2, , );
  PH128(1, 3, , );
#undef PH128
#undef WAITV

  const int orow = by * 128 + (lane >> 4) * 4;
  const int ocol = nOff + bx * 256 + wn + lr;
#pragma unroll
  for (int m = 0; m < 8; ++m)
#pragma unroll
    for (int n = 0; n < 2; ++n)
#pragma unroll
      for (int r = 0; r < 4; ++r)
        C[(size_t)(orow + m * 16 + r) * Ncols + (ocol + n * 16)] = (OutT)acc[m][n][r];
}

// ---------------- rope + rms-norm, in-place on q,k inside qkv buffer --------
__global__ __launch_bounds__(256) void rope_rms(
    bf16* __restrict__ qkv, const float* __restrict__ cs,
    const float* __restrict__ sn, int T) {
  const int C = N_HEAD * HEAD_DIM;
  const int S = 3 * C;
  const int bt = blockIdx.x;
  const int t = bt % T;
  const int wave = threadIdx.x >> 6;
  const int lane = threadIdx.x & 63;
  const int h = blockIdx.y * 4 + wave;
  bf16* p = qkv + (size_t)bt * S + (blockIdx.z ? C : 0) + h * HEAD_DIM;
  // q: 1.2 * 0.08838834764831845 * 1.4426950408889634 (exp2-domain softmax)
  const float oscale = blockIdx.z ? 1.2f : 0.15302091809294977f;
  const float c = cs[t * 64 + lane];
  const float s = sn[t * 64 + lane];
  const float x1 = (float)p[lane];
  const float x2 = (float)p[lane + 64];
  const float r1 = x1 * c + x2 * s;
  const float r2 = x2 * c - x1 * s;
  float ss = r1 * r1 + r2 * r2;
#pragma unroll
  for (int m = 1; m < 64; m <<= 1) ss += __shfl_xor(ss, m);
  const float sc = oscale * rsqrtf(ss * (1.0f / 128.0f) + 1e-6f);
  p[lane] = (bf16)(r1 * sc);
  p[lane + 64] = (bf16)(r2 * sc);
}

// ---------------- gate + transpose: vT[b][h][d][t] = v[b][t][h][d] + gate*ve --
__global__ __launch_bounds__(256) void gate_transpose(
    const bf16* __restrict__ qkv, const float* __restrict__ x,
    const float* __restrict__ ve, const float* __restrict__ Wg,
    bf16* __restrict__ vT, int T) {
  const int C = N_HEAD * HEAD_DIM;
  const int S = 3 * C;
  const int t0 = blockIdx.x * 64;
  const int c0 = blockIdx.y * 64;
  const int b = blockIdx.z;
  const int h = c0 >> 7;

  __shared__ float gs[64];
  __shared__ __align__(16) bf16 tile[64][72];

  if (threadIdx.x < 64) {
    const float* xr = x + (size_t)(b * T + t0 + threadIdx.x) * C;
    float a = 0.f;
#pragma unroll
    for (int j = 0; j < 12; ++j) a += xr[j] * Wg[h * 12 + j];
    gs[threadIdx.x] = 3.f / (1.f + __expf(-a));
  }
  __syncthreads();

  {
    const int r = threadIdx.x >> 2;
    const int cc = (threadIdx.x & 3) * 16;
    const size_t vrow = (size_t)(b * T + t0 + r) * S + 2 * C + c0 + cc;
    const size_t erow = (size_t)(b * T + t0 + r) * C + c0 + cc;
    bf16x8 a0 = *reinterpret_cast<const bf16x8*>(qkv + vrow);
    bf16x8 a1 = *reinterpret_cast<const bf16x8*>(qkv + vrow + 8);
    const float g = gs[r];
    bf16x8 o0, o1;
#pragma unroll
    for (int i = 0; i < 8; ++i) o0[i] = (bf16)((float)a0[i] + g * ve[erow + i]);
#pragma unroll
    for (int i = 0; i < 8; ++i) o1[i] = (bf16)((float)a1[i] + g * ve[erow + 8 + i]);
    *reinterpret_cast<bf16x8*>(&tile[r][cc]) = o0;
    *reinterpret_cast<bf16x8*>(&tile[r][cc + 8]) = o1;
  }
  __syncthreads();
  {
    const int dr = threadIdx.x >> 2;        // col of tile = d offset
    const int tc = (threadIdx.x & 3) * 16;  // row of tile = t offset
    bf16x8 o0, o1;
#pragma unroll
    for (int i = 0; i < 8; ++i) o0[i] = tile[tc + i][dr];
#pragma unroll
    for (int i = 0; i < 8; ++i) o1[i] = tile[tc + 8 + i][dr];
    const size_t orow =
        ((size_t)((b * N_HEAD + h) * HEAD_DIM) + (c0 & 127) + dr) * T + t0 + tc;
    *reinterpret_cast<bf16x8*>(vT + orow) = o0;
    *reinterpret_cast<bf16x8*>(vT + orow + 8) = o1;
  }
}

// ---------------- flash attention, sliding window, LDS-staged --------------
// Round-4 rework: (1) all LDS tiles use 128B-granule XOR swizzle
// elem ^= ((row&7)<<3) -> every ds_read/ds_write gives 8 consecutive lanes
// 8 distinct bank groups (GEMM-verified T2 pattern, conflicts ~0).
// (2) K/V fragments are read ONCE and shared by both q-tiles (P gets a t-dim
// in LDS) -> LDS read traffic per chunk drops 34KB/wave -> 20KB/wave.
// (3) single-compare window mask; O-rescale skipped when max didn't grow.
__global__ __launch_bounds__(256, 2) void attn(
    const bf16* __restrict__ qkv, const bf16* __restrict__ vT,
    bf16* __restrict__ y, const int* __restrict__ wptr, int T, int B) {
  const int C = N_HEAD * HEAD_DIM;
  const int S = 3 * C;
  const int nq = T >> 7;                       // q-blocks per (b,h)
  const int ppx = (B * N_HEAD) >> 3;           // (b,h) pairs per XCD
  const int bid = blockIdx.x;
  const int xcd = bid & 7;
  const int sl = bid >> 3;
  const int pair = xcd * ppx + sl / nq;
  const int qi = sl % nq;
  const int b = pair / N_HEAD;
  const int h = pair % N_HEAD;
  const int qb = qi * 128;

  const int tid = threadIdx.x;
  const int wave = tid >> 6;
  const int lane = tid & 63;
  const int lm = lane & 15;
  const int quad = lane >> 4;
  const int lmw = (lm & 7) << 3;  // read-side swizzle XOR (elem units)

  const int w = wptr[0];
  const int W = (w > 0 && w < T) ? w : (1 << 30);

  __shared__ __align__(16) bf16 Ks[64][128];       // [key][d]        16 KB
  __shared__ __align__(16) bf16 Vs[128][64];       // [d][key]        16 KB
  __shared__ __align__(16) bf16 Pb[4][2][16][64];  // [wave][t][q][k] 16 KB

  const bf16* kb = qkv + (size_t)b * T * S + C + (size_t)h * HEAD_DIM;
  const bf16* vb = vT + (size_t)((b * N_HEAD + h) * HEAD_DIM) * T;  // [128][T]

  const int qt[2] = {qb + wave * 16, qb + 64 + wave * 16};
  bf16x8 qf[2][4];
#pragma unroll
  for (int t = 0; t < 2; ++t) {
    const bf16* qrow = qkv + (size_t)(b * T + qt[t] + lm) * S + h * HEAD_DIM;
#pragma unroll
    for (int c = 0; c < 4; ++c)
      qf[t][c] = *reinterpret_cast<const bf16x8*>(qrow + c * 32 + quad * 8);
  }

  float mrun[2] = {-1e30f, -1e30f}, lrun[2] = {0.f, 0.f};
  f32x4 oacc[2][8] = {};

  int kstart = qb - W;
  if (kstart < 0) kstart = 0;
  kstart &= ~63;
  const int kend = qb + 64;  // last chunk start

  const int sr = tid >> 2;        // staging row 0..63
  const int s4 = (tid & 3) * 8;   // element offset of this thread's 16B unit
  const int swz = (sr & 7) << 3;  // staging-write swizzle XOR

  bf16x8 kpre[4], vpre[4];
  {
    const bf16* kr = kb + (size_t)(kstart + sr) * S;
#pragma unroll
    for (int c = 0; c < 4; ++c)
      kpre[c] = *reinterpret_cast<const bf16x8*>(kr + c * 32 + s4);
#pragma unroll
    for (int c2 = 0; c2 < 2; ++c2)
#pragma unroll
      for (int i = 0; i < 2; ++i)
        vpre[c2 * 2 + i] = *reinterpret_cast<const bf16x8*>(
            vb + (size_t)(i * 64 + sr) * T + kstart + c2 * 32 + s4);
  }

  // per-t softmax: mask, row-max, (conditional) rescale, exp -> Pb[wave][t]
#define SOFTMAX_PB(t, st)                                                   \
  {                                                                         \
    const int qr = qt[t] + lm;                                              \
    float mx = -1e30f;                                                      \
    _Pragma("unroll") for (int g = 0; g < 4; ++g)                           \
    _Pragma("unroll") for (int r = 0; r < 4; ++r) {                         \
      const int key = kc + g * 16 + quad * 4 + r;                           \
      const bool valid = (unsigned)(qr - key) <= (unsigned)W;               \
      st[g][r] = valid ? st[g][r] : -1e30f;                                 \
      mx = fmaxf(mx, st[g][r]);                                             \
    }                                                                       \
    mx = fmaxf(mx, __shfl_xor(mx, 16));                                     \
    mx = fmaxf(mx, __shfl_xor(mx, 32));                                     \
    float alpha = 1.f;                                                      \
    if (!__all(mx <= mrun[t])) {                                            \
      const float mnew = fmaxf(mrun[t], mx);                                \
      alpha = __builtin_amdgcn_exp2f(mrun[t] - mnew);                       \
      mrun[t] = mnew;                                                       \
      _Pragma("unroll") for (int dc = 0; dc < 8; ++dc)                      \
      _Pragma("unroll") for (int r = 0; r < 4; ++r) oacc[t][dc][r] *= alpha;\
    }                                                                       \
    float rs = 0.f;                                                         \
    _Pragma("unroll") for (int g = 0; g < 4; ++g) {                         \
      bf16x4 pk;                                                            \
      _Pragma("unroll") for (int r = 0; r < 4; ++r) {                       \
        const float p = __builtin_amdgcn_exp2f(st[g][r] - mrun[t]);         \
        rs += p;                                                            \
        pk[r] = (bf16)p;                                                    \
      }                                                                     \
      *reinterpret_cast<bf16x4*>(                                           \
          &Pb[wave][t][lm][((g * 16 + (quad >> 1) * 8) ^ lmw) +             \
                           (quad & 1) * 4]) = pk;                           \
    }                                                                       \
    rs += __shfl_xor(rs, 16);                                               \
    rs += __shfl_xor(rs, 32);                                               \
    lrun[t] = lrun[t] * alpha + rs;                                         \
  }

  // single-tile fallback (first/last chunks where only one t is in-window)
#define SINGLE_PASS(t)                                                      \
  {                                                                         \
    f32x4 st[4] = {};                                                       \
    _Pragma("unroll") for (int g = 0; g < 4; ++g)                           \
    _Pragma("unroll") for (int c = 0; c < 4; ++c) {                         \
      const bf16x8 kf = *reinterpret_cast<const bf16x8*>(                   \
          &Ks[g * 16 + lm][(c * 32 + quad * 8) ^ lmw]);                     \
      st[g] = __builtin_amdgcn_mfma_f32_16x16x32_bf16(kf, qf[t][c], st[g],  \
                                                      0, 0, 0);             \
    }                                                                       \
    SOFTMAX_PB(t, st);                                                      \
    _Pragma("unroll") for (int c2 = 0; c2 < 2; ++c2) {                      \
      const bf16x8 pf = *reinterpret_cast<const bf16x8*>(                   \
          &Pb[wave][t][lm][(c2 * 32 + quad * 8) ^ lmw]);                    \
      _Pragma("unroll") for (int dc = 0; dc < 8; ++dc) {                    \
        const bf16x8 vf = *reinterpret_cast<const bf16x8*>(                 \
            &Vs[dc * 16 + lm][(c2 * 32 + quad * 8) ^ lmw]);                 \
        oacc[t][dc] = __builtin_amdgcn_mfma_f32_16x16x32_bf16(              \
            vf, pf, oacc[t][dc], 0, 0, 0);                                  \
      }                                                                     \
    }                                                                       \
  }

  for (int kc = kstart; kc <= kend; kc += 64) {
    __syncthreads();
    // commit prefetched chunk (swizzled linear ds_write, conflict-free)
#pragma unroll
    for (int c = 0; c < 4; ++c)
      *reinterpret_cast<bf16x8*>(&Ks[sr][(c * 32 + s4) ^ swz]) = kpre[c];
#pragma unroll
    for (int c2 = 0; c2 < 2; ++c2)
#pragma unroll
      for (int i = 0; i < 2; ++i)
        *reinterpret_cast<bf16x8*>(&Vs[i * 64 + sr][(c2 * 32 + s4) ^ swz]) =
            vpre[c2 * 2 + i];
    __syncthreads();

    // issue next chunk's global loads before compute
    if (kc + 64 <= kend) {
      const int kc2 = kc + 64;
      const bf16* kr = kb + (size_t)(kc2 + sr) * S;
#pragma unroll
      for (int c = 0; c < 4; ++c)
        kpre[c] = *reinterpret_cast<const bf16x8*>(kr + c * 32 + s4);
#pragma unroll
      for (int c2 = 0; c2 < 2; ++c2)
#pragma unroll
        for (int i = 0; i < 2; ++i)
          vpre[c2 * 2 + i] = *reinterpret_cast<const bf16x8*>(
              vb + (size_t)(i * 64 + sr) * T + kc2 + c2 * 32 + s4);
    }

    const bool a0 = !(kc > qt[0] + 15 || kc + 63 < qt[0] - W);
    const bool a1 = !(kc > qt[1] + 15 || kc + 63 < qt[1] - W);

    if (a0 & a1) {
      // merged path: each K/V fragment read once, feeds both q-tiles
      f32x4 s0[4] = {}, s1[4] = {};
#pragma unroll
      for (int g = 0; g < 4; ++g)
#pragma unroll
        for (int c = 0; c < 4; ++c) {
          const bf16x8 kf = *reinterpret_cast<const bf16x8*>(
              &Ks[g * 16 + lm][(c * 32 + quad * 8) ^ lmw]);
          s0[g] = __builtin_amdgcn_mfma_f32_16x16x32_bf16(kf, qf[0][c], s0[g], 0, 0, 0);
          s1[g] = __builtin_amdgcn_mfma_f32_16x16x32_bf16(kf, qf[1][c], s1[g], 0, 0, 0);
        }
      SOFTMAX_PB(0, s0);
      SOFTMAX_PB(1, s1);
#pragma unroll
      for (int c2 = 0; c2 < 2; ++c2) {
        const bf16x8 pf0 = *reinterpret_cast<const bf16x8*>(
            &Pb[wave][0][lm][(c2 * 32 + quad * 8) ^ lmw]);
        const bf16x8 pf1 = *reinterpret_cast<const bf16x8*>(
            &Pb[wave][1][lm][(c2 * 32 + quad * 8) ^ lmw]);
#pragma unroll
        for (int dc = 0; dc < 8; ++dc) {
          const bf16x8 vf = *reinterpret_cast<const bf16x8*>(
              &Vs[dc * 16 + lm][(c2 * 32 + quad * 8) ^ lmw]);
          oacc[0][dc] = __builtin_amdgcn_mfma_f32_16x16x32_bf16(vf, pf0, oacc[0][dc], 0, 0, 0);
          oacc[1][dc] = __builtin_amdgcn_mfma_f32_16x16x32_bf16(vf, pf1, oacc[1][dc], 0, 0, 0);
        }
      }
    } else if (a0) {
      SINGLE_PASS(0);
    } else if (a1) {
      SINGLE_PASS(1);
    }
  }
#undef SINGLE_PASS
#undef SOFTMAX_PB

#pragma unroll
  for (int t = 0; t < 2; ++t) {
    const float inv = 1.f / lrun[t];
    bf16* yr = y + (size_t)(b * T + qt[t] + lm) * C + h * HEAD_DIM;
#pragma unroll
    for (int dc = 0; dc < 8; ++dc) {
      bf16x4 o;
#pragma unroll
      for (int r = 0; r < 4; ++r) o[r] = (bf16)(oacc[t][dc][r] * inv);
      *reinterpret_cast<bf16x4*>(yr + dc * 16 + quad * 4) = o;
    }
  }
}

extern "C" void kernel_launch(void* const* d_in, const int* in_sizes, int n_in,
                              void* d_out, int out_size, void* d_ws, size_t ws_size,
                              hipStream_t stream) {
  const float* x  = (const float*)d_in[0];
  const float* ve = (const float*)d_in[1];
  const float* Wq = (const float*)d_in[2];
  const float* Wk = (const float*)d_in[3];
  const float* Wv = (const float*)d_in[4];
  const float* Wp = (const float*)d_in[5];
  const float* Wg = (const float*)d_in[6];
  const float* cs = (const float*)d_in[7];
  const float* sn = (const float*)d_in[8];
  const int*   wl = (const int*)d_in[9];
  float* out = (float*)d_out;

  const int C = N_HEAD * HEAD_DIM;       // 2048
  const int T = in_sizes[7] / (HEAD_DIM / 2);
  const int B = in_sizes[0] / (T * C);
  const int M = B * T;

  bf16* xb   = (bf16*)d_ws;                    // [M][C]
  bf16* wqkv = xb   + (size_t)M * C;           // [3C][C] (Wq|Wk|Wv rows)
  bf16* wpb  = wqkv + (size_t)3 * C * C;       // [C][C]
  bf16* qkv  = wpb  + (size_t)C * C;           // [M][3C]
  bf16* ybuf = qkv  + (size_t)3 * M * C;       // [M][C]
  bf16* vTb  = xb;  // xb dead after QKV GEMM; reuse for V^T [B][H][128][T]

  const int nx4 = M * C / 4, nw4 = C * C / 4;
  cvt_all<<<dim3((nx4 + 255) / 256, 1, 5), 256, 0, stream>>>(
      x, Wq, Wk, Wv, Wp, xb, wqkv, wpb, nx4, nw4);

  // QKV split for exact-round grids (256 CUs, 1 block/CU):
  // part 1: Q|K cols 0..4095  -> gemm256, (4096/256)*16 = 256 blocks
  // part 2: V  cols 4096..6143 -> gemm128, (4096/128)*8 = 256 blocks
  gemm256<<<dim3((M / 256) * 16), 512, 0, stream>>>(xb, wqkv, qkv, M, 3 * C, C);
  gemm128<bf16><<<dim3((M / 128) * 8), 512, 0, stream>>>(
      xb, wqkv, qkv, M, 3 * C, C, 2 * C);

  rope_rms<<<dim3(M, N_HEAD / 4, 2), 256, 0, stream>>>(qkv, cs, sn, T);
  gate_transpose<<<dim3(T / 64, C / 64, B), 256, 0, stream>>>(qkv, x, ve, Wg, vTb, T);
  attn<<<dim3(B * N_HEAD * (T / 128)), 256, 0, stream>>>(qkv, vTb, ybuf, wl, T, B);

  // projection: [M,2048] = ybuf * wpb^T -> gemm128<float>, 32*8 = 256 blocks
  gemm128<float><<<dim3((M / 128) * (C / 256)), 512, 0, stream>>>(
      ybuf, wpb, out, M, C, C, 0);
}